// Round 3
// baseline (212.917 us; speedup 1.0000x reference)
//
#include <hip/hip_runtime.h>

#define NN 10000
#define DF 128
#define NE 640000

__device__ __forceinline__ unsigned short f2bf(float f) {
    unsigned int u = __float_as_uint(f);
    u = (u + 0x7FFFu + ((u >> 16) & 1u)) >> 16;   // round-to-nearest-even
    return (unsigned short)u;
}
__device__ __forceinline__ float bf_lo(unsigned int v) {  // element stored in bits [15:0]
    return __uint_as_float(v << 16);
}
__device__ __forceinline__ float bf_hi(unsigned int v) {  // element stored in bits [31:16]
    return __uint_as_float(v & 0xFFFF0000u);
}

// ---------------------------------------------------------------------------
// K1: Xs_bf = bf16(feat @ W_src^T + b_src)   [NN x 128] packed as uint pairs.
// Lane = row. blockIdx.y picks a 16-wide output tile; W accesses are
// wave-uniform -> s_load (SGPR operand), so zero LDS and zero ds_read.
// y==0 blocks also zero cnt[] (runs before hist_deg in stream order).
// ---------------------------------------------------------------------------
__global__ __launch_bounds__(64) void xform_src(const float* __restrict__ feat,
                                                const float* __restrict__ W,
                                                const float* __restrict__ b,
                                                unsigned int* __restrict__ Xs_bf,
                                                int* __restrict__ cnt, int n)
{
    const int row   = blockIdx.x * 64 + threadIdx.x;
    const int obase = blockIdx.y * 16;

    if (blockIdx.y == 0) {
        const int gid = blockIdx.x * 64 + threadIdx.x;
        if (gid < NN) cnt[gid] = 0;
    }
    if (row >= n) return;

    float acc[16];
#pragma unroll
    for (int o = 0; o < 16; ++o) acc[o] = b[obase + o];

    const float4* f4 = (const float4*)(feat + (size_t)row * DF);
    for (int k4 = 0; k4 < 32; ++k4) {
        const float4 f = f4[k4];
#pragma unroll
        for (int o = 0; o < 16; ++o) {
            const float* w = W + (size_t)(obase + o) * DF + k4 * 4;  // uniform -> SGPR
            acc[o] += f.x * w[0] + f.y * w[1] + f.z * w[2] + f.w * w[3];
        }
    }
    // pack 16 outputs -> 8 uints (bf16 pairs), 32B contiguous per lane
    unsigned int* dst = Xs_bf + (size_t)row * 64 + obase / 2;
#pragma unroll
    for (int p = 0; p < 8; ++p) {
        unsigned int lo = f2bf(acc[2 * p]);
        unsigned int hi = f2bf(acc[2 * p + 1]);
        dst[p] = lo | (hi << 16);
    }
}

// ---------------------------------------------------------------------------
// K2a: in-degree histogram (int atomics)
// ---------------------------------------------------------------------------
__global__ __launch_bounds__(256) void hist_deg(const int* __restrict__ dst,
                                                int* __restrict__ cnt, int nE)
{
    const int e = blockIdx.x * 256 + threadIdx.x;
    if (e < nE) atomicAdd(&cnt[dst[e]], 1);
}

// ---------------------------------------------------------------------------
// K2b: exclusive scan cnt -> off, then zero cnt (it becomes the scatter
// cursor). Single 1024-thread block, 10 elems/thread.
// ---------------------------------------------------------------------------
__global__ __launch_bounds__(1024) void scan_offsets(int* __restrict__ cnt,
                                                     int* __restrict__ off)
{
    __shared__ int part[1024];
    const int t = threadIdx.x;
    const int base = t * 10;
    int local[10];
    int s = 0;
    for (int i = 0; i < 10; ++i) {
        int idx = base + i;
        int c = (idx < NN) ? cnt[idx] : 0;
        if (idx < NN) cnt[idx] = 0;          // reset -> cursor for scatter_idx
        local[i] = s;
        s += c;
    }
    part[t] = s;
    __syncthreads();
    for (int d = 1; d < 1024; d <<= 1) {
        int v = (t >= d) ? part[t - d] : 0;
        __syncthreads();
        part[t] += v;
        __syncthreads();
    }
    const int pre = (t == 0) ? 0 : part[t - 1];
    for (int i = 0; i < 10; ++i) {
        int idx = base + i;
        if (idx < NN) off[idx] = pre + local[i];
    }
    if (t == 1023) off[NN] = part[1023];
}

// ---------------------------------------------------------------------------
// K2c: scatter src ids into CSR buckets (cnt is the zeroed cursor).
// ---------------------------------------------------------------------------
__global__ __launch_bounds__(256) void scatter_idx(const int* __restrict__ src,
                                                   const int* __restrict__ dst,
                                                   const int* __restrict__ off,
                                                   int* __restrict__ cnt,
                                                   int* __restrict__ srcs, int nE)
{
    const int e = blockIdx.x * 256 + threadIdx.x;
    if (e < nE) {
        const int d = dst[e];
        const int p = atomicAdd(&cnt[d], 1);
        srcs[off[d] + p] = src[e];
    }
}

// ---------------------------------------------------------------------------
// K3: neigh[v] = mean of Xs_bf[src] rows. Wave per node; lane owns 2 features
// (one uint = 2 bf16). Xs_bf is 2.5MB -> fits each XCD's L2.
// ---------------------------------------------------------------------------
__global__ __launch_bounds__(256) void gather_mean(const unsigned int* __restrict__ Xs_bf,
                                                   const int* __restrict__ srcs,
                                                   const int* __restrict__ off,
                                                   float* __restrict__ neigh, int n)
{
    const int wave = threadIdx.x >> 6, lane = threadIdx.x & 63;
    const int v = blockIdx.x * 4 + wave;
    if (v >= n) return;
    const int s0 = off[v], s1 = off[v + 1];
    const int cnt = s1 - s0;

    float ax = 0.f, ay = 0.f;
    int i = s0;
    for (; i + 4 <= s1; i += 4) {
        const int ia = srcs[i + 0];
        const int ib = srcs[i + 1];
        const int ic = srcs[i + 2];
        const int id = srcs[i + 3];
        const unsigned int a = Xs_bf[(size_t)ia * 64 + lane];
        const unsigned int b = Xs_bf[(size_t)ib * 64 + lane];
        const unsigned int c = Xs_bf[(size_t)ic * 64 + lane];
        const unsigned int d = Xs_bf[(size_t)id * 64 + lane];
        ax += (bf_lo(a) + bf_lo(b)) + (bf_lo(c) + bf_lo(d));
        ay += (bf_hi(a) + bf_hi(b)) + (bf_hi(c) + bf_hi(d));
    }
    for (; i < s1; ++i) {
        const unsigned int a = Xs_bf[(size_t)srcs[i] * 64 + lane];
        ax += bf_lo(a); ay += bf_hi(a);
    }
    const float inv = (cnt > 0) ? (1.0f / (float)cnt) : 0.0f;
    float2 o; o.x = ax * inv; o.y = ay * inv;
    *(float2*)(neigh + (size_t)v * DF + lane * 2) = o;
}

// ---------------------------------------------------------------------------
// K4: out = feat @ Wfc[:, :128]^T + neigh @ Wfc[:, 128:]^T + b_fc
// Same SGPR-weight structure as K1; K=256 split into two 128 halves.
// ---------------------------------------------------------------------------
__global__ __launch_bounds__(64) void apply_fc(const float* __restrict__ feat,
                                               const float* __restrict__ neigh,
                                               const float* __restrict__ Wfc,
                                               const float* __restrict__ bfc,
                                               float* __restrict__ out, int n)
{
    const int row   = blockIdx.x * 64 + threadIdx.x;
    const int obase = blockIdx.y * 16;
    if (row >= n) return;

    float acc[16];
#pragma unroll
    for (int o = 0; o < 16; ++o) acc[o] = bfc[obase + o];

    const float4* f4 = (const float4*)(feat + (size_t)row * DF);
    for (int k4 = 0; k4 < 32; ++k4) {
        const float4 f = f4[k4];
#pragma unroll
        for (int o = 0; o < 16; ++o) {
            const float* w = Wfc + (size_t)(obase + o) * 256 + k4 * 4;  // uniform
            acc[o] += f.x * w[0] + f.y * w[1] + f.z * w[2] + f.w * w[3];
        }
    }
    const float4* n4 = (const float4*)(neigh + (size_t)row * DF);
    for (int k4 = 0; k4 < 32; ++k4) {
        const float4 a = n4[k4];
#pragma unroll
        for (int o = 0; o < 16; ++o) {
            const float* w = Wfc + (size_t)(obase + o) * 256 + 128 + k4 * 4;  // uniform
            acc[o] += a.x * w[0] + a.y * w[1] + a.z * w[2] + a.w * w[3];
        }
    }
    float* orow = out + (size_t)row * DF + obase;
#pragma unroll
    for (int o4 = 0; o4 < 4; ++o4) {
        float4 v = make_float4(acc[4 * o4 + 0], acc[4 * o4 + 1],
                               acc[4 * o4 + 2], acc[4 * o4 + 3]);
        *(float4*)(orow + 4 * o4) = v;
    }
}

extern "C" void kernel_launch(void* const* d_in, const int* in_sizes, int n_in,
                              void* d_out, int out_size, void* d_ws, size_t ws_size,
                              hipStream_t stream) {
    const float* feat  = (const float*)d_in[0];   // [NN, 128]
    const float* W_src = (const float*)d_in[1];   // [128, 128]
    const float* b_src = (const float*)d_in[2];   // [128]
    const float* W_fc  = (const float*)d_in[3];   // [128, 256]
    const float* b_fc  = (const float*)d_in[4];   // [128]
    const int*   src   = (const int*)d_in[5];     // [NE]
    const int*   dst   = (const int*)d_in[6];     // [NE]
    float* out = (float*)d_out;

    // workspace layout:
    // Xs_bf [NN*64 uint] | neigh [NN*128 f32] | cnt [NN] | off [NN+1] | srcs [NE]
    unsigned int* Xs_bf = (unsigned int*)d_ws;
    float* neigh = (float*)(Xs_bf + (size_t)NN * 64);
    int*   cnt   = (int*)(neigh + (size_t)NN * DF);
    int*   off   = cnt + NN;
    int*   srcs  = off + (NN + 1);

    const int rowblks = (NN + 63) / 64;  // 157

    xform_src  <<<dim3(rowblks, 8), 64, 0, stream>>>(feat, W_src, b_src, Xs_bf, cnt, NN);
    hist_deg   <<<(NE + 255) / 256, 256, 0, stream>>>(dst, cnt, NE);
    scan_offsets<<<1, 1024, 0, stream>>>(cnt, off);
    scatter_idx<<<(NE + 255) / 256, 256, 0, stream>>>(src, dst, off, cnt, srcs, NE);
    gather_mean<<<(NN + 3) / 4, 256, 0, stream>>>(Xs_bf, srcs, off, neigh, NN);
    apply_fc   <<<dim3(rowblks, 8), 64, 0, stream>>>(feat, neigh, W_fc, b_fc, out, NN);
}